// Round 2
// baseline (1104.651 us; speedup 1.0000x reference)
//
#include <hip/hip_runtime.h>
#include <hip/hip_bf16.h>

typedef __bf16 bf16_t;
typedef bf16_t bf16x8 __attribute__((ext_vector_type(8)));
typedef bf16_t bf16x2 __attribute__((ext_vector_type(2)));
typedef float  f32x4  __attribute__((ext_vector_type(4)));

#define EPS 1e-5f

// ---------------------------------------------------------------------------
// Prep: BN fold + weight transpose/convert into MFMA B-fragment layout.
// B-frag for 16x16x32 mfma: frag[(kt*NT + nt)*64 + lane][j] = W[nt*16 + (lane&15)][kt*32 + (lane>>4)*8 + j]
// ---------------------------------------------------------------------------
__global__ __launch_bounds__(256) void prep_kernel(
    const float* __restrict__ op_w1, const float* __restrict__ op_w2,
    const float* __restrict__ nm_w1, const float* __restrict__ nm_w2,
    const float* __restrict__ op_g, const float* __restrict__ op_b,
    const float* __restrict__ op_m, const float* __restrict__ op_v,
    const float* __restrict__ nm_g, const float* __restrict__ nm_b,
    const float* __restrict__ nm_m, const float* __restrict__ nm_v,
    bf16_t* __restrict__ w1f, bf16_t* __restrict__ w2f,
    bf16_t* __restrict__ nw1f, bf16_t* __restrict__ nw2f,
    float* __restrict__ opsc, float* __restrict__ opsh,
    float* __restrict__ nmsc, float* __restrict__ nmsh)
{
    int t = blockIdx.x * 256 + threadIdx.x;
    if (t < 4096) {                       // op_w1: [256 out][128 in] -> [kt<4][nt<16][64][8]
        int g = t, lane = g & 63, nt = (g >> 6) & 15, kt = g >> 10;
        int n = nt * 16 + (lane & 15);
        int k0 = kt * 32 + (lane >> 4) * 8;
        const float* src = op_w1 + (size_t)n * 128 + k0;
        bf16x8 v;
        for (int j = 0; j < 8; ++j) v[j] = (bf16_t)src[j];
        *(bf16x8*)(w1f + (size_t)g * 8) = v;
    } else if (t < 12288) {               // op_w2: [256][256] -> [kt<8][nt<16][64][8]
        int g = t - 4096, lane = g & 63, nt = (g >> 6) & 15, kt = g >> 10;
        int n = nt * 16 + (lane & 15);
        int k0 = kt * 32 + (lane >> 4) * 8;
        const float* src = op_w2 + (size_t)n * 256 + k0;
        bf16x8 v;
        for (int j = 0; j < 8; ++j) v[j] = (bf16_t)src[j];
        *(bf16x8*)(w2f + (size_t)g * 8) = v;
    } else if (t < 14336) {               // nm_w1: [128][128] -> [kt<4][nt<8][64][8]
        int g = t - 12288, lane = g & 63, nt = (g >> 6) & 7, kt = g >> 9;
        int n = nt * 16 + (lane & 15);
        int k0 = kt * 32 + (lane >> 4) * 8;
        const float* src = nm_w1 + (size_t)n * 128 + k0;
        bf16x8 v;
        for (int j = 0; j < 8; ++j) v[j] = (bf16_t)src[j];
        *(bf16x8*)(nw1f + (size_t)g * 8) = v;
    } else if (t < 16384) {               // nm_w2: [128][128] -> [kt<4][nt<8][64][8]
        int g = t - 14336, lane = g & 63, nt = (g >> 6) & 7, kt = g >> 9;
        int n = nt * 16 + (lane & 15);
        int k0 = kt * 32 + (lane >> 4) * 8;
        const float* src = nm_w2 + (size_t)n * 128 + k0;
        bf16x8 v;
        for (int j = 0; j < 8; ++j) v[j] = (bf16_t)src[j];
        *(bf16x8*)(nw2f + (size_t)g * 8) = v;
    } else if (t < 16512) {               // op BN fold
        int c = t - 16384;
        float s = op_g[c] / sqrtf(op_v[c] + EPS);
        opsc[c] = s;
        opsh[c] = op_b[c] - op_m[c] * s;
    } else if (t < 16640) {               // nm BN fold
        int c = t - 16512;
        float s = nm_g[c] / sqrtf(nm_v[c] + EPS);
        nmsc[c] = s;
        nmsh[c] = nm_b[c] - nm_m[c] * s;
    }
}

// ---------------------------------------------------------------------------
// Kernel 1: fused BN + Linear(128->256) + ReLU + Linear(256->256) -> y (bf16)
// 64 tokens / block, 4 waves, wave mt owns token rows [mt*16, mt*16+16).
// No atomics: y is streamed out; the scatter-sum happens in gather_mlp2.
// ---------------------------------------------------------------------------
__global__ __launch_bounds__(256) void mlp1_y(
    const float* __restrict__ x,
    const float* __restrict__ opsc, const float* __restrict__ opsh,
    const bf16_t* __restrict__ w1f, const bf16_t* __restrict__ w2f,
    const float* __restrict__ b1, const float* __restrict__ b2,
    bf16_t* __restrict__ y, int T)
{
    __shared__ __align__(16) bf16_t Ax[4 * 4 * 64 * 8];   // [mt][kt<4][lane][8]  16 KB
    __shared__ __align__(16) bf16_t Hf[4 * 8 * 64 * 8];   // [mt][kt<8][lane][8]  32 KB
    const int tid  = threadIdx.x;
    const int base = blockIdx.x * 64;

    // ---- stage X tile with BN folded, into A-fragment layout ----
    {
        const int rr = tid >> 4;      // 0..15
        const int kg = tid & 15;      // 8-col group
        const int c0 = kg * 8;
        float sc[8], sh[8];
        for (int j = 0; j < 8; ++j) { sc[j] = opsc[c0 + j]; sh[j] = opsh[c0 + j]; }
        for (int p = 0; p < 4; ++p) {
            int r   = p * 16 + rr;
            int tok = base + r;
            float f[8];
            if (tok < T) {
                const float4* xp = (const float4*)(x + (size_t)tok * 128 + c0);
                float4 u = xp[0], w = xp[1];
                f[0] = u.x; f[1] = u.y; f[2] = u.z; f[3] = u.w;
                f[4] = w.x; f[5] = w.y; f[6] = w.z; f[7] = w.w;
            } else {
                for (int j = 0; j < 8; ++j) f[j] = 0.f;
            }
            bf16x8 v;
            for (int j = 0; j < 8; ++j) v[j] = (bf16_t)(f[j] * sc[j] + sh[j]);
            int flat = (((r >> 4) * 4 + (kg >> 2)) * 64 + (kg & 3) * 16 + (r & 15)) * 8;
            *(bf16x8*)(Ax + flat) = v;
        }
    }
    __syncthreads();

    const int mt    = tid >> 6;
    const int l     = tid & 63;
    const int colL  = l & 15;
    const int quadw = l >> 4;

    // ---- GEMM1: H = relu(Xbn * W1^T + b1), write H as A-frags to LDS ----
    bf16x8 a1[4];
    for (int kt = 0; kt < 4; ++kt)
        a1[kt] = *(const bf16x8*)(Ax + ((mt * 4 + kt) * 64 + l) * 8);
    for (int nt = 0; nt < 16; ++nt) {
        f32x4 acc = {0.f, 0.f, 0.f, 0.f};
        for (int kt = 0; kt < 4; ++kt) {
            bf16x8 b = *(const bf16x8*)(w1f + (size_t)((kt * 16 + nt) * 64 + l) * 8);
            acc = __builtin_amdgcn_mfma_f32_16x16x32_bf16(a1[kt], b, acc, 0, 0, 0);
        }
        float bb = b1[nt * 16 + colL];
        int c   = nt * 16 + colL;
        int kt2 = c >> 5, q2 = (c >> 3) & 3, j2 = c & 7;
        int hbase = ((mt * 8 + kt2) * 64 + q2 * 16) * 8 + j2;
        for (int reg = 0; reg < 4; ++reg) {
            float h = acc[reg] + bb;
            h = h > 0.f ? h : 0.f;
            int m2 = quadw * 4 + reg;
            Hf[hbase + m2 * 8] = (bf16_t)h;
        }
    }

    // ---- GEMM2: Y = H * W2^T + b2, stream to y as bf16 ----
    bf16x8 a2[8];
    for (int kt = 0; kt < 8; ++kt)
        a2[kt] = *(const bf16x8*)(Hf + ((mt * 8 + kt) * 64 + l) * 8);
    for (int nt = 0; nt < 16; ++nt) {
        f32x4 acc = {0.f, 0.f, 0.f, 0.f};
        for (int kt = 0; kt < 8; ++kt) {
            bf16x8 b = *(const bf16x8*)(w2f + (size_t)((kt * 16 + nt) * 64 + l) * 8);
            acc = __builtin_amdgcn_mfma_f32_16x16x32_bf16(a2[kt], b, acc, 0, 0, 0);
        }
        float bb = b2[nt * 16 + colL];
        int c = nt * 16 + colL;
        for (int reg = 0; reg < 4; ++reg) {
            int row = base + mt * 16 + quadw * 4 + reg;
            if (row < T) y[(size_t)row * 256 + c] = (bf16_t)(acc[reg] + bb);
        }
    }
}

// ---------------------------------------------------------------------------
// CSR build: count -> scan (3 kernels) -> fill
// ---------------------------------------------------------------------------
__global__ __launch_bounds__(256) void count_kernel(
    const int* __restrict__ tix, int* __restrict__ cnt, int T2)
{
    int i = blockIdx.x * 256 + threadIdx.x;
    if (i < T2) atomicAdd(&cnt[tix[i]], 1);
}

__global__ __launch_bounds__(256) void scan1(
    const int* __restrict__ cnt, int* __restrict__ bsum, int N)
{
    __shared__ int lds[256];
    int t = threadIdx.x;
    int i0 = blockIdx.x * 1024 + t * 4;
    int s = 0;
    for (int j = 0; j < 4; ++j) { int i = i0 + j; s += (i < N) ? cnt[i] : 0; }
    lds[t] = s; __syncthreads();
    for (int off = 1; off < 256; off <<= 1) {
        int v = (t >= off) ? lds[t - off] : 0;
        __syncthreads(); lds[t] += v; __syncthreads();
    }
    if (t == 255) bsum[blockIdx.x] = lds[255];
}

__global__ __launch_bounds__(256) void scan2(
    const int* __restrict__ bsum, int* __restrict__ bpref, int nb)
{
    __shared__ int lds[256];
    int t = threadIdx.x;
    int s = (t < nb) ? bsum[t] : 0;
    lds[t] = s; __syncthreads();
    for (int off = 1; off < 256; off <<= 1) {
        int v = (t >= off) ? lds[t - off] : 0;
        __syncthreads(); lds[t] += v; __syncthreads();
    }
    if (t < nb) bpref[t] = lds[t] - s;   // exclusive
}

__global__ __launch_bounds__(256) void scan3(
    const int* __restrict__ cnt, const int* __restrict__ bpref,
    int* __restrict__ offs, int* __restrict__ run, int N)
{
    __shared__ int lds[256];
    int t = threadIdx.x;
    int i0 = blockIdx.x * 1024 + t * 4;
    int c[4]; int s = 0;
    for (int j = 0; j < 4; ++j) { int i = i0 + j; c[j] = (i < N) ? cnt[i] : 0; s += c[j]; }
    lds[t] = s; __syncthreads();
    for (int off = 1; off < 256; off <<= 1) {
        int v = (t >= off) ? lds[t - off] : 0;
        __syncthreads(); lds[t] += v; __syncthreads();
    }
    int p = lds[t] - s + bpref[blockIdx.x];
    for (int j = 0; j < 4; ++j) {
        int i = i0 + j;
        if (i < N) { offs[i] = p; run[i] = p; }
        p += c[j];
    }
}

__global__ __launch_bounds__(256) void fill_kernel(
    const int* __restrict__ tix, int* __restrict__ run,
    int* __restrict__ entries, int T2, int T)
{
    int i = blockIdx.x * 256 + threadIdx.x;
    if (i < T2) {
        int n = tix[i];
        int s = (i >= T) ? 1 : 0;
        int t = s ? (i - T) : i;
        int pos = atomicAdd(&run[n], 1);
        entries[pos] = (t << 1) | s;
    }
}

// ---------------------------------------------------------------------------
// Kernel 2: gather (segment-sum of y) + node MLP fused, writes d_out.
// 64 nodes / block; wave w gathers nodes [w*16, w*16+16), lane l covers
// columns {2l, 2l+1}; staged directly into MFMA A-fragment layout in LDS.
// ---------------------------------------------------------------------------
__global__ __launch_bounds__(256) void gather_mlp2(
    const bf16_t* __restrict__ y,
    const int* __restrict__ offs, const int* __restrict__ cnt,
    const int* __restrict__ entries,
    const float* __restrict__ nmsc, const float* __restrict__ nmsh,
    const bf16_t* __restrict__ w1f, const bf16_t* __restrict__ w2f,
    const float* __restrict__ b1, const float* __restrict__ b2,
    float* __restrict__ out, int N)
{
    __shared__ __align__(16) bf16_t Ax[4 * 4 * 64 * 8];   // 16 KB
    __shared__ __align__(16) bf16_t Hf[4 * 4 * 64 * 8];   // 16 KB
    const int tid  = threadIdx.x;
    const int base = blockIdx.x * 64;
    const int w    = tid >> 6;
    const int l    = tid & 63;

    // ---- gather + BN fold, write A-frags ----
    {
        const int c0  = 2 * l;
        float sc0 = nmsc[c0], sc1 = nmsc[c0 + 1];
        float sh0 = nmsh[c0], sh1 = nmsh[c0 + 1];
        for (int i = 0; i < 16; ++i) {
            int r = w * 16 + i;          // local row; r>>4 == w, r&15 == i
            int n = base + r;
            float a0 = 0.f, a1 = 0.f;
            if (n < N) {
                int e0 = offs[n], c = cnt[n];
                for (int e = 0; e < c; ++e) {
                    int ent = entries[e0 + e];
                    int t = ent >> 1, s = ent & 1;
                    bf16x2 v = *(const bf16x2*)(y + (size_t)t * 256 + s * 128 + c0);
                    a0 += (float)v[0];
                    a1 += (float)v[1];
                }
            }
            a0 = a0 * sc0 + sh0;
            a1 = a1 * sc1 + sh1;
            int idx = ((w * 4 + (c0 >> 5)) * 64 + ((c0 >> 3) & 3) * 16 + i) * 8 + (c0 & 7);
            bf16x2 pv; pv[0] = (bf16_t)a0; pv[1] = (bf16_t)a1;
            *(bf16x2*)(Ax + idx) = pv;
        }
    }
    __syncthreads();

    const int mt    = w;
    const int colL  = l & 15;
    const int quadw = l >> 4;

    bf16x8 a1f[4];
    for (int kt = 0; kt < 4; ++kt)
        a1f[kt] = *(const bf16x8*)(Ax + ((mt * 4 + kt) * 64 + l) * 8);
    for (int nt = 0; nt < 8; ++nt) {
        f32x4 acc = {0.f, 0.f, 0.f, 0.f};
        for (int kt = 0; kt < 4; ++kt) {
            bf16x8 b = *(const bf16x8*)(w1f + (size_t)((kt * 8 + nt) * 64 + l) * 8);
            acc = __builtin_amdgcn_mfma_f32_16x16x32_bf16(a1f[kt], b, acc, 0, 0, 0);
        }
        float bb = b1[nt * 16 + colL];
        int c   = nt * 16 + colL;
        int kt2 = c >> 5, q2 = (c >> 3) & 3, j2 = c & 7;
        int hbase = ((mt * 4 + kt2) * 64 + q2 * 16) * 8 + j2;
        for (int reg = 0; reg < 4; ++reg) {
            float h = acc[reg] + bb;
            h = h > 0.f ? h : 0.f;
            int m2 = quadw * 4 + reg;
            Hf[hbase + m2 * 8] = (bf16_t)h;
        }
    }

    bf16x8 a2f[4];
    for (int kt = 0; kt < 4; ++kt)
        a2f[kt] = *(const bf16x8*)(Hf + ((mt * 4 + kt) * 64 + l) * 8);
    for (int nt = 0; nt < 8; ++nt) {
        f32x4 acc = {0.f, 0.f, 0.f, 0.f};
        for (int kt = 0; kt < 4; ++kt) {
            bf16x8 b = *(const bf16x8*)(w2f + (size_t)((kt * 8 + nt) * 64 + l) * 8);
            acc = __builtin_amdgcn_mfma_f32_16x16x32_bf16(a2f[kt], b, acc, 0, 0, 0);
        }
        float bb = b2[nt * 16 + colL];
        int c = nt * 16 + colL;
        for (int reg = 0; reg < 4; ++reg) {
            int row = base + mt * 16 + quadw * 4 + reg;
            if (row < N) out[(size_t)row * 128 + c] = acc[reg] + bb;
        }
    }
}

// ---------------------------------------------------------------------------
extern "C" void kernel_launch(void* const* d_in, const int* in_sizes, int n_in,
                              void* d_out, int out_size, void* d_ws, size_t ws_size,
                              hipStream_t stream)
{
    const float* x     = (const float*)d_in[0];
    const int*   tix   = (const int*)d_in[3];
    const float* op_g  = (const float*)d_in[4];
    const float* op_b  = (const float*)d_in[5];
    const float* op_m  = (const float*)d_in[6];
    const float* op_v  = (const float*)d_in[7];
    const float* op_w1 = (const float*)d_in[8];
    const float* op_b1 = (const float*)d_in[9];
    const float* op_w2 = (const float*)d_in[10];
    const float* op_b2 = (const float*)d_in[11];
    const float* nm_g  = (const float*)d_in[12];
    const float* nm_b  = (const float*)d_in[13];
    const float* nm_m  = (const float*)d_in[14];
    const float* nm_v  = (const float*)d_in[15];
    const float* nm_w1 = (const float*)d_in[16];
    const float* nm_b1 = (const float*)d_in[17];
    const float* nm_w2 = (const float*)d_in[18];
    const float* nm_b2 = (const float*)d_in[19];

    const int T  = in_sizes[0] / 128;
    const int N  = in_sizes[2];
    const int T2 = 2 * T;

    char* w = (char*)d_ws;
    size_t off = 0;
    bf16_t* y = (bf16_t*)w;              off += (size_t)T * 256 * 2;
    off = (off + 255) & ~(size_t)255;
    bf16_t* w1f  = (bf16_t*)(w + off);   off += (size_t)4096 * 8 * 2;
    bf16_t* w2f  = (bf16_t*)(w + off);   off += (size_t)8192 * 8 * 2;
    bf16_t* nw1f = (bf16_t*)(w + off);   off += (size_t)2048 * 8 * 2;
    bf16_t* nw2f = (bf16_t*)(w + off);   off += (size_t)2048 * 8 * 2;
    float* opsc  = (float*)(w + off);    off += 512;
    float* opsh  = (float*)(w + off);    off += 512;
    float* nmsc  = (float*)(w + off);    off += 512;
    float* nmsh  = (float*)(w + off);    off += 512;
    int* cnt     = (int*)(w + off);      off += (size_t)N * 4;
    int* offs    = (int*)(w + off);      off += (size_t)N * 4;
    int* run     = (int*)(w + off);      off += (size_t)N * 4;
    int* bsum    = (int*)(w + off);      off += 1024 * 4;
    int* bpref   = (int*)(w + off);      off += 1024 * 4;
    int* entries = (int*)(w + off);      off += (size_t)T2 * 4;

    const int nb = (N + 1023) / 1024;    // scan blocks (must be <= 256)

    hipMemsetAsync(cnt, 0, (size_t)N * 4, stream);
    prep_kernel<<<65, 256, 0, stream>>>(op_w1, op_w2, nm_w1, nm_w2,
                                        op_g, op_b, op_m, op_v,
                                        nm_g, nm_b, nm_m, nm_v,
                                        w1f, w2f, nw1f, nw2f,
                                        opsc, opsh, nmsc, nmsh);
    mlp1_y<<<(T + 63) / 64, 256, 0, stream>>>(x, opsc, opsh, w1f, w2f,
                                              op_b1, op_b2, y, T);
    count_kernel<<<(T2 + 255) / 256, 256, 0, stream>>>(tix, cnt, T2);
    scan1<<<nb, 256, 0, stream>>>(cnt, bsum, N);
    scan2<<<1, 256, 0, stream>>>(bsum, bpref, nb);
    scan3<<<nb, 256, 0, stream>>>(cnt, bpref, offs, run, N);
    fill_kernel<<<(T2 + 255) / 256, 256, 0, stream>>>(tix, run, entries, T2, T);
    gather_mlp2<<<(N + 63) / 64, 256, 0, stream>>>(y, offs, cnt, entries,
                                                   nmsc, nmsh, nw1f, nw2f,
                                                   nm_b1, nm_b2, (float*)d_out, N);
}

// Round 3
// 787.294 us; speedup vs baseline: 1.4031x; 1.4031x over previous
//
#include <hip/hip_runtime.h>
#include <hip/hip_bf16.h>

typedef __bf16 bf16_t;
typedef bf16_t bf16x8 __attribute__((ext_vector_type(8)));
typedef bf16_t bf16x4 __attribute__((ext_vector_type(4)));
typedef bf16_t bf16x2 __attribute__((ext_vector_type(2)));
typedef float  f32x4  __attribute__((ext_vector_type(4)));

#define EPS 1e-5f

// ---------------------------------------------------------------------------
// Prep: BN fold + weight transpose/convert into MFMA B-fragment layout.
// B-frag for 16x16x32 mfma: frag[(kt*NT + nt)*64 + lane][j] = W[nt*16 + (lane&15)][kt*32 + (lane>>4)*8 + j]
// ---------------------------------------------------------------------------
__global__ __launch_bounds__(256) void prep_kernel(
    const float* __restrict__ op_w1, const float* __restrict__ op_w2,
    const float* __restrict__ nm_w1, const float* __restrict__ nm_w2,
    const float* __restrict__ op_g, const float* __restrict__ op_b,
    const float* __restrict__ op_m, const float* __restrict__ op_v,
    const float* __restrict__ nm_g, const float* __restrict__ nm_b,
    const float* __restrict__ nm_m, const float* __restrict__ nm_v,
    bf16_t* __restrict__ w1f, bf16_t* __restrict__ w2f,
    bf16_t* __restrict__ nw1f, bf16_t* __restrict__ nw2f,
    float* __restrict__ opsc, float* __restrict__ opsh,
    float* __restrict__ nmsc, float* __restrict__ nmsh)
{
    int t = blockIdx.x * 256 + threadIdx.x;
    if (t < 4096) {                       // op_w1: [256 out][128 in] -> [kt<4][nt<16][64][8]
        int g = t, lane = g & 63, nt = (g >> 6) & 15, kt = g >> 10;
        int n = nt * 16 + (lane & 15);
        int k0 = kt * 32 + (lane >> 4) * 8;
        const float* src = op_w1 + (size_t)n * 128 + k0;
        bf16x8 v;
        for (int j = 0; j < 8; ++j) v[j] = (bf16_t)src[j];
        *(bf16x8*)(w1f + (size_t)g * 8) = v;
    } else if (t < 12288) {               // op_w2: [256][256] -> [kt<8][nt<16][64][8]
        int g = t - 4096, lane = g & 63, nt = (g >> 6) & 15, kt = g >> 10;
        int n = nt * 16 + (lane & 15);
        int k0 = kt * 32 + (lane >> 4) * 8;
        const float* src = op_w2 + (size_t)n * 256 + k0;
        bf16x8 v;
        for (int j = 0; j < 8; ++j) v[j] = (bf16_t)src[j];
        *(bf16x8*)(w2f + (size_t)g * 8) = v;
    } else if (t < 14336) {               // nm_w1: [128][128] -> [kt<4][nt<8][64][8]
        int g = t - 12288, lane = g & 63, nt = (g >> 6) & 7, kt = g >> 9;
        int n = nt * 16 + (lane & 15);
        int k0 = kt * 32 + (lane >> 4) * 8;
        const float* src = nm_w1 + (size_t)n * 128 + k0;
        bf16x8 v;
        for (int j = 0; j < 8; ++j) v[j] = (bf16_t)src[j];
        *(bf16x8*)(nw1f + (size_t)g * 8) = v;
    } else if (t < 16384) {               // nm_w2: [128][128] -> [kt<4][nt<8][64][8]
        int g = t - 14336, lane = g & 63, nt = (g >> 6) & 7, kt = g >> 9;
        int n = nt * 16 + (lane & 15);
        int k0 = kt * 32 + (lane >> 4) * 8;
        const float* src = nm_w2 + (size_t)n * 128 + k0;
        bf16x8 v;
        for (int j = 0; j < 8; ++j) v[j] = (bf16_t)src[j];
        *(bf16x8*)(nw2f + (size_t)g * 8) = v;
    } else if (t < 16512) {               // op BN fold
        int c = t - 16384;
        float s = op_g[c] / sqrtf(op_v[c] + EPS);
        opsc[c] = s;
        opsh[c] = op_b[c] - op_m[c] * s;
    } else if (t < 16640) {               // nm BN fold
        int c = t - 16512;
        float s = nm_g[c] / sqrtf(nm_v[c] + EPS);
        nmsc[c] = s;
        nmsh[c] = nm_b[c] - nm_m[c] * s;
    }
}

// ---------------------------------------------------------------------------
// Kernel 1: fused BN + Linear(128->256) + ReLU + Linear(256->256) -> y (bf16)
// 64 tokens / block, 4 waves. N-split: wave w owns output col-tiles nt with
// nt%4==w, for ALL 4 row-tiles -> each B-fragment is loaded once per block
// (not once per wave) and feeds 4 (GEMM1) / 2 (GEMM2, m-paired) MFMAs.
// ---------------------------------------------------------------------------
__global__ __launch_bounds__(256) void mlp1_y(
    const float* __restrict__ x,
    const float* __restrict__ opsc, const float* __restrict__ opsh,
    const bf16_t* __restrict__ w1f, const bf16_t* __restrict__ w2f,
    const float* __restrict__ b1, const float* __restrict__ b2,
    bf16_t* __restrict__ y, int T)
{
    __shared__ __align__(16) bf16_t Ax[4 * 4 * 64 * 8];   // [m<4][kt<4][lane][8]  16 KB
    __shared__ __align__(16) bf16_t Hf[4 * 8 * 64 * 8];   // [m<4][kt<8][lane][8]  32 KB
    const int tid  = threadIdx.x;
    const int base = blockIdx.x * 64;

    // ---- stage X tile with BN folded, into A-fragment layout ----
    {
        const int rr = tid >> 4;      // 0..15
        const int kg = tid & 15;      // 8-col group
        const int c0 = kg * 8;
        float sc[8], sh[8];
        for (int j = 0; j < 8; ++j) { sc[j] = opsc[c0 + j]; sh[j] = opsh[c0 + j]; }
        for (int p = 0; p < 4; ++p) {
            int r   = p * 16 + rr;
            int tok = base + r;
            float f[8];
            if (tok < T) {
                const float4* xp = (const float4*)(x + (size_t)tok * 128 + c0);
                float4 u = xp[0], w = xp[1];
                f[0] = u.x; f[1] = u.y; f[2] = u.z; f[3] = u.w;
                f[4] = w.x; f[5] = w.y; f[6] = w.z; f[7] = w.w;
            } else {
                for (int j = 0; j < 8; ++j) f[j] = 0.f;
            }
            bf16x8 v;
            for (int j = 0; j < 8; ++j) v[j] = (bf16_t)(f[j] * sc[j] + sh[j]);
            int flat = (((r >> 4) * 4 + (kg >> 2)) * 64 + (kg & 3) * 16 + (r & 15)) * 8;
            *(bf16x8*)(Ax + flat) = v;
        }
    }
    __syncthreads();

    const int w     = tid >> 6;       // wave id = nt residue
    const int l     = tid & 63;
    const int colL  = l & 15;
    const int quadw = l >> 4;

    // ---- GEMM1: H = relu(Xbn * W1^T + b1); wave w does nt%4==w, all m ----
    {
        bf16x8 a1[16];                 // [m][kt]
        for (int m = 0; m < 4; ++m)
            for (int kt = 0; kt < 4; ++kt)
                a1[m * 4 + kt] = *(const bf16x8*)(Ax + ((m * 4 + kt) * 64 + l) * 8);
        for (int nt_l = 0; nt_l < 4; ++nt_l) {
            const int nt = nt_l * 4 + w;
            f32x4 acc[4];
            for (int m = 0; m < 4; ++m) acc[m] = (f32x4){0.f, 0.f, 0.f, 0.f};
            for (int kt = 0; kt < 4; ++kt) {
                bf16x8 b = *(const bf16x8*)(w1f + (size_t)((kt * 16 + nt) * 64 + l) * 8);
                for (int m = 0; m < 4; ++m)
                    acc[m] = __builtin_amdgcn_mfma_f32_16x16x32_bf16(a1[m * 4 + kt], b, acc[m], 0, 0, 0);
            }
            float bb = b1[nt * 16 + colL];
            int c   = nt * 16 + colL;
            int kt2 = c >> 5, q2 = (c >> 3) & 3, j2 = c & 7;
            for (int m = 0; m < 4; ++m) {
                int hbase = ((m * 8 + kt2) * 64 + q2 * 16) * 8 + j2;
                for (int reg = 0; reg < 4; ++reg) {
                    float h = acc[m][reg] + bb;
                    h = h > 0.f ? h : 0.f;
                    int m2 = quadw * 4 + reg;
                    Hf[hbase + m2 * 8] = (bf16_t)h;
                }
            }
        }
    }
    __syncthreads();

    // ---- GEMM2: Y = H * W2^T + b2; wave w does nt%4==w, m in pairs ----
    for (int mp = 0; mp < 2; ++mp) {
        bf16x8 a2[16];                 // [mm<2][kt<8]
        for (int mm = 0; mm < 2; ++mm)
            for (int kt = 0; kt < 8; ++kt)
                a2[mm * 8 + kt] = *(const bf16x8*)(Hf + (((2 * mp + mm) * 8 + kt) * 64 + l) * 8);
        for (int nt_l = 0; nt_l < 4; ++nt_l) {
            const int nt = nt_l * 4 + w;
            f32x4 acc0 = {0.f, 0.f, 0.f, 0.f};
            f32x4 acc1 = {0.f, 0.f, 0.f, 0.f};
            for (int kt = 0; kt < 8; ++kt) {
                bf16x8 b = *(const bf16x8*)(w2f + (size_t)((kt * 16 + nt) * 64 + l) * 8);
                acc0 = __builtin_amdgcn_mfma_f32_16x16x32_bf16(a2[kt],     b, acc0, 0, 0, 0);
                acc1 = __builtin_amdgcn_mfma_f32_16x16x32_bf16(a2[8 + kt], b, acc1, 0, 0, 0);
            }
            float bb = b2[nt * 16 + colL];
            int c = nt * 16 + colL;
            for (int reg = 0; reg < 4; ++reg) {
                int r0 = base + (2 * mp) * 16 + quadw * 4 + reg;
                int r1 = base + (2 * mp + 1) * 16 + quadw * 4 + reg;
                if (r0 < T) y[(size_t)r0 * 256 + c] = (bf16_t)(acc0[reg] + bb);
                if (r1 < T) y[(size_t)r1 * 256 + c] = (bf16_t)(acc1[reg] + bb);
            }
        }
    }
}

// ---------------------------------------------------------------------------
// CSR build: count -> scan (3 kernels) -> fill
// ---------------------------------------------------------------------------
__global__ __launch_bounds__(256) void count_kernel(
    const int* __restrict__ tix, int* __restrict__ cnt, int T2)
{
    int i = blockIdx.x * 256 + threadIdx.x;
    if (i < T2) atomicAdd(&cnt[tix[i]], 1);
}

__global__ __launch_bounds__(256) void scan1(
    const int* __restrict__ cnt, int* __restrict__ bsum, int N)
{
    __shared__ int lds[256];
    int t = threadIdx.x;
    int i0 = blockIdx.x * 1024 + t * 4;
    int s = 0;
    for (int j = 0; j < 4; ++j) { int i = i0 + j; s += (i < N) ? cnt[i] : 0; }
    lds[t] = s; __syncthreads();
    for (int off = 1; off < 256; off <<= 1) {
        int v = (t >= off) ? lds[t - off] : 0;
        __syncthreads(); lds[t] += v; __syncthreads();
    }
    if (t == 255) bsum[blockIdx.x] = lds[255];
}

__global__ __launch_bounds__(256) void scan2(
    const int* __restrict__ bsum, int* __restrict__ bpref, int nb)
{
    __shared__ int lds[256];
    int t = threadIdx.x;
    int s = (t < nb) ? bsum[t] : 0;
    lds[t] = s; __syncthreads();
    for (int off = 1; off < 256; off <<= 1) {
        int v = (t >= off) ? lds[t - off] : 0;
        __syncthreads(); lds[t] += v; __syncthreads();
    }
    if (t < nb) bpref[t] = lds[t] - s;   // exclusive
}

__global__ __launch_bounds__(256) void scan3(
    const int* __restrict__ cnt, const int* __restrict__ bpref,
    int* __restrict__ offs, int* __restrict__ run, int N)
{
    __shared__ int lds[256];
    int t = threadIdx.x;
    int i0 = blockIdx.x * 1024 + t * 4;
    int c[4]; int s = 0;
    for (int j = 0; j < 4; ++j) { int i = i0 + j; c[j] = (i < N) ? cnt[i] : 0; s += c[j]; }
    lds[t] = s; __syncthreads();
    for (int off = 1; off < 256; off <<= 1) {
        int v = (t >= off) ? lds[t - off] : 0;
        __syncthreads(); lds[t] += v; __syncthreads();
    }
    int p = lds[t] - s + bpref[blockIdx.x];
    for (int j = 0; j < 4; ++j) {
        int i = i0 + j;
        if (i < N) { offs[i] = p; run[i] = p; }
        p += c[j];
    }
}

__global__ __launch_bounds__(256) void fill_kernel(
    const int* __restrict__ tix, int* __restrict__ run,
    int* __restrict__ entries, int T2, int T)
{
    int i = blockIdx.x * 256 + threadIdx.x;
    if (i < T2) {
        int n = tix[i];
        int s = (i >= T) ? 1 : 0;
        int t = s ? (i - T) : i;
        int pos = atomicAdd(&run[n], 1);
        entries[pos] = (t << 1) | s;   // y offset of entry = ent*128
    }
}

// ---------------------------------------------------------------------------
// Kernel 2: gather (segment-sum of y) + node MLP fused, writes d_out.
// 64 nodes / block. Gather: each wave processes 2 nodes at a time (half-wave
// per node, 32 lanes x 4 cols), entry loop unrolled x4 -> ~8 independent
// 256-B gathers in flight per wave. Staged into MFMA A-fragment layout.
// ---------------------------------------------------------------------------
__global__ __launch_bounds__(256) void gather_mlp2(
    const bf16_t* __restrict__ y,
    const int* __restrict__ offs, const int* __restrict__ cnt,
    const int* __restrict__ entries,
    const float* __restrict__ nmsc, const float* __restrict__ nmsh,
    const bf16_t* __restrict__ w1f, const bf16_t* __restrict__ w2f,
    const float* __restrict__ b1, const float* __restrict__ b2,
    float* __restrict__ out, int N)
{
    __shared__ __align__(16) bf16_t Ax[4 * 4 * 64 * 8];   // 16 KB
    __shared__ __align__(16) bf16_t Hf[4 * 4 * 64 * 8];   // 16 KB
    const int tid  = threadIdx.x;
    const int base = blockIdx.x * 64;
    const int w    = tid >> 6;
    const int l    = tid & 63;

    // ---- gather + BN fold, write A-frags ----
    {
        const int half = l >> 5;          // which of 2 concurrent nodes
        const int cl   = l & 31;
        const int c0   = cl * 4;          // 4 columns per lane
        float sc[4], sh[4];
        for (int j = 0; j < 4; ++j) { sc[j] = nmsc[c0 + j]; sh[j] = nmsh[c0 + j]; }
        for (int ii = 0; ii < 8; ++ii) {
            int r = w * 16 + ii * 2 + half;
            int n = base + r;
            float a[4] = {0.f, 0.f, 0.f, 0.f};
            if (n < N) {
                int e0 = offs[n], c = cnt[n];
                int e = 0;
                for (; e + 4 <= c; e += 4) {
                    int t0 = entries[e0 + e];
                    int t1 = entries[e0 + e + 1];
                    int t2 = entries[e0 + e + 2];
                    int t3 = entries[e0 + e + 3];
                    bf16x4 v0 = *(const bf16x4*)(y + (size_t)t0 * 128 + c0);
                    bf16x4 v1 = *(const bf16x4*)(y + (size_t)t1 * 128 + c0);
                    bf16x4 v2 = *(const bf16x4*)(y + (size_t)t2 * 128 + c0);
                    bf16x4 v3 = *(const bf16x4*)(y + (size_t)t3 * 128 + c0);
                    for (int j = 0; j < 4; ++j)
                        a[j] += ((float)v0[j] + (float)v1[j]) + ((float)v2[j] + (float)v3[j]);
                }
                for (; e < c; ++e) {
                    int t0 = entries[e0 + e];
                    bf16x4 v0 = *(const bf16x4*)(y + (size_t)t0 * 128 + c0);
                    for (int j = 0; j < 4; ++j) a[j] += (float)v0[j];
                }
            }
            bf16x4 pv;
            for (int j = 0; j < 4; ++j) pv[j] = (bf16_t)(a[j] * sc[j] + sh[j]);
            int idx = ((w * 4 + (c0 >> 5)) * 64 + ((c0 >> 3) & 3) * 16 + (r & 15)) * 8 + (c0 & 7);
            *(bf16x4*)(Ax + idx) = pv;
        }
    }
    __syncthreads();

    const int mt    = w;
    const int colL  = l & 15;
    const int quadw = l >> 4;

    bf16x8 a1f[4];
    for (int kt = 0; kt < 4; ++kt)
        a1f[kt] = *(const bf16x8*)(Ax + ((mt * 4 + kt) * 64 + l) * 8);
    for (int nt = 0; nt < 8; ++nt) {
        f32x4 acc = {0.f, 0.f, 0.f, 0.f};
        for (int kt = 0; kt < 4; ++kt) {
            bf16x8 b = *(const bf16x8*)(w1f + (size_t)((kt * 8 + nt) * 64 + l) * 8);
            acc = __builtin_amdgcn_mfma_f32_16x16x32_bf16(a1f[kt], b, acc, 0, 0, 0);
        }
        float bb = b1[nt * 16 + colL];
        int c   = nt * 16 + colL;
        int kt2 = c >> 5, q2 = (c >> 3) & 3, j2 = c & 7;
        int hbase = ((mt * 4 + kt2) * 64 + q2 * 16) * 8 + j2;
        for (int reg = 0; reg < 4; ++reg) {
            float h = acc[reg] + bb;
            h = h > 0.f ? h : 0.f;
            int m2 = quadw * 4 + reg;
            Hf[hbase + m2 * 8] = (bf16_t)h;
        }
    }

    bf16x8 a2f[4];
    for (int kt = 0; kt < 4; ++kt)
        a2f[kt] = *(const bf16x8*)(Hf + ((mt * 4 + kt) * 64 + l) * 8);
    for (int nt = 0; nt < 8; ++nt) {
        f32x4 acc = {0.f, 0.f, 0.f, 0.f};
        for (int kt = 0; kt < 4; ++kt) {
            bf16x8 b = *(const bf16x8*)(w2f + (size_t)((kt * 8 + nt) * 64 + l) * 8);
            acc = __builtin_amdgcn_mfma_f32_16x16x32_bf16(a2f[kt], b, acc, 0, 0, 0);
        }
        float bb = b2[nt * 16 + colL];
        int c = nt * 16 + colL;
        for (int reg = 0; reg < 4; ++reg) {
            int row = base + mt * 16 + quadw * 4 + reg;
            if (row < N) out[(size_t)row * 128 + c] = acc[reg] + bb;
        }
    }
}

// ---------------------------------------------------------------------------
extern "C" void kernel_launch(void* const* d_in, const int* in_sizes, int n_in,
                              void* d_out, int out_size, void* d_ws, size_t ws_size,
                              hipStream_t stream)
{
    const float* x     = (const float*)d_in[0];
    const int*   tix   = (const int*)d_in[3];
    const float* op_g  = (const float*)d_in[4];
    const float* op_b  = (const float*)d_in[5];
    const float* op_m  = (const float*)d_in[6];
    const float* op_v  = (const float*)d_in[7];
    const float* op_w1 = (const float*)d_in[8];
    const float* op_b1 = (const float*)d_in[9];
    const float* op_w2 = (const float*)d_in[10];
    const float* op_b2 = (const float*)d_in[11];
    const float* nm_g  = (const float*)d_in[12];
    const float* nm_b  = (const float*)d_in[13];
    const float* nm_m  = (const float*)d_in[14];
    const float* nm_v  = (const float*)d_in[15];
    const float* nm_w1 = (const float*)d_in[16];
    const float* nm_b1 = (const float*)d_in[17];
    const float* nm_w2 = (const float*)d_in[18];
    const float* nm_b2 = (const float*)d_in[19];

    const int T  = in_sizes[0] / 128;
    const int N  = in_sizes[2];
    const int T2 = 2 * T;

    char* w = (char*)d_ws;
    size_t off = 0;
    bf16_t* y = (bf16_t*)w;              off += (size_t)T * 256 * 2;
    off = (off + 255) & ~(size_t)255;
    bf16_t* w1f  = (bf16_t*)(w + off);   off += (size_t)4096 * 8 * 2;
    bf16_t* w2f  = (bf16_t*)(w + off);   off += (size_t)8192 * 8 * 2;
    bf16_t* nw1f = (bf16_t*)(w + off);   off += (size_t)2048 * 8 * 2;
    bf16_t* nw2f = (bf16_t*)(w + off);   off += (size_t)2048 * 8 * 2;
    float* opsc  = (float*)(w + off);    off += 512;
    float* opsh  = (float*)(w + off);    off += 512;
    float* nmsc  = (float*)(w + off);    off += 512;
    float* nmsh  = (float*)(w + off);    off += 512;
    int* cnt     = (int*)(w + off);      off += (size_t)N * 4;
    int* offs    = (int*)(w + off);      off += (size_t)N * 4;
    int* run     = (int*)(w + off);      off += (size_t)N * 4;
    int* bsum    = (int*)(w + off);      off += 1024 * 4;
    int* bpref   = (int*)(w + off);      off += 1024 * 4;
    int* entries = (int*)(w + off);      off += (size_t)T2 * 4;

    const int nb = (N + 1023) / 1024;    // scan blocks (must be <= 256)

    hipMemsetAsync(cnt, 0, (size_t)N * 4, stream);
    prep_kernel<<<65, 256, 0, stream>>>(op_w1, op_w2, nm_w1, nm_w2,
                                        op_g, op_b, op_m, op_v,
                                        nm_g, nm_b, nm_m, nm_v,
                                        w1f, w2f, nw1f, nw2f,
                                        opsc, opsh, nmsc, nmsh);
    mlp1_y<<<(T + 63) / 64, 256, 0, stream>>>(x, opsc, opsh, w1f, w2f,
                                              op_b1, op_b2, y, T);
    count_kernel<<<(T2 + 255) / 256, 256, 0, stream>>>(tix, cnt, T2);
    scan1<<<nb, 256, 0, stream>>>(cnt, bsum, N);
    scan2<<<1, 256, 0, stream>>>(bsum, bpref, nb);
    scan3<<<nb, 256, 0, stream>>>(cnt, bpref, offs, run, N);
    fill_kernel<<<(T2 + 255) / 256, 256, 0, stream>>>(tix, run, entries, T2, T);
    gather_mlp2<<<(N + 63) / 64, 256, 0, stream>>>(y, offs, cnt, entries,
                                                   nmsc, nmsh, nw1f, nw2f,
                                                   nm_b1, nm_b2, (float*)d_out, N);
}